// Round 6
// baseline (34323.819 us; speedup 1.0000x reference)
//
#include <hip/hip_runtime.h>
#include <stdint.h>

#define B_ 128
#define T_ 256
#define F_ 128
#define NCAT_ 32
#define CARD_ 16
#define E_ 8
#define H_ 512
#define INLEN_ 352
#define NCONT_ 96

typedef __bf16 bf16x8 __attribute__((ext_vector_type(8)));
typedef float f32x4 __attribute__((ext_vector_type(4)));
typedef unsigned short ushortx8 __attribute__((ext_vector_type(8)));
typedef unsigned int u32x4_ __attribute__((ext_vector_type(4)));

__device__ __forceinline__ unsigned short f2bf(float f) {
  unsigned int u = __float_as_uint(f);
  u += 0x7fffu + ((u >> 16) & 1u);   // RNE
  return (unsigned short)(u >> 16);
}
__device__ __forceinline__ float sigm(float x) { return 1.0f / (1.0f + __expf(-x)); }
__device__ __forceinline__ float tanhf_(float x) {
  float a = fabsf(x);
  float e = __expf(-2.0f * a);
  float t = (1.0f - e) / (1.0f + e);
  return x < 0.0f ? -t : t;
}

// ---------------- prep: W_in transposed -> bf16 (512 x 352) ----------------
__global__ void k_prep(const float* __restrict__ W_in, unsigned short* __restrict__ W_inT) {
  int id = blockIdx.x * 256 + threadIdx.x;
  if (id < 512 * INLEN_) {
    int n = id / INLEN_;
    int k = id - n * INLEN_;
    W_inT[id] = f2bf(W_in[k * 512 + n]);
  }
}

// ---------------- features: FEAT[t*128+b][352] bf16 ----------------
__global__ void k_feat(const int* __restrict__ unscaled, const float* __restrict__ scaled,
                       const float* __restrict__ emb, unsigned short* __restrict__ FEAT) {
  int row = blockIdx.x * 4 + (threadIdx.x >> 6);
  int t = row >> 7, b = row & 127;
  const int base = (b * T_ + t) * F_;
  for (int jj = (threadIdx.x & 63); jj < INLEN_; jj += 64) {
    int ci = jj / 11;
    int pos = jj - ci * 11;
    float v;
    if (pos < 8) {
      int cid = unscaled[base + 4 * ci];
      v = emb[(ci * CARD_ + cid) * E_ + pos];
    } else {
      v = scaled[base + 4 * ci + 1 + (pos - 8)];
    }
    FEAT[row * INLEN_ + jj] = f2bf(v);
  }
}

// ---------------- GEMM1: X = relu(FEAT @ W_in + b_in), bf16 out ----------------
__global__ __launch_bounds__(256) void k_gemm1(const unsigned short* __restrict__ FEAT,
                                               const unsigned short* __restrict__ W_inT,
                                               const float* __restrict__ b_in,
                                               unsigned short* __restrict__ X) {
  __shared__ __align__(16) unsigned short As[128 * 40];
  __shared__ __align__(16) unsigned short Bs[128 * 40];
  const int tid = threadIdx.x;
  const int Mtile = blockIdx.x >> 2;
  const int N0 = (blockIdx.x & 3) * 128;
  const int wv = tid >> 6, ln = tid & 63;
  const int lrow = ln & 15, lq = ln >> 4;
  f32x4 acc[2][8];
#pragma unroll
  for (int i = 0; i < 2; ++i)
#pragma unroll
    for (int j = 0; j < 8; ++j) acc[i][j] = (f32x4){0.f, 0.f, 0.f, 0.f};

  for (int kc = 0; kc < 11; ++kc) {
    int k0 = kc * 32;
#pragma unroll
    for (int i = 0; i < 2; ++i) {
      int c = i * 256 + tid;
      int row = c >> 2;
      int col = (c & 3) * 8;
      uint4 va = *(const uint4*)&FEAT[(Mtile * 128 + row) * INLEN_ + k0 + col];
      *(uint4*)&As[row * 40 + col] = va;
      uint4 vb = *(const uint4*)&W_inT[(N0 + row) * INLEN_ + k0 + col];
      *(uint4*)&Bs[row * 40 + col] = vb;
    }
    __syncthreads();
    bf16x8 af[2];
#pragma unroll
    for (int mt = 0; mt < 2; ++mt) {
      int r = wv * 32 + mt * 16 + lrow;
      af[mt] = __builtin_bit_cast(bf16x8, *(const ushortx8*)&As[r * 40 + lq * 8]);
    }
#pragma unroll
    for (int ntl = 0; ntl < 8; ++ntl) {
      bf16x8 bf = __builtin_bit_cast(bf16x8, *(const ushortx8*)&Bs[(ntl * 16 + lrow) * 40 + lq * 8]);
      acc[0][ntl] = __builtin_amdgcn_mfma_f32_16x16x32_bf16(af[0], bf, acc[0][ntl], 0, 0, 0);
      acc[1][ntl] = __builtin_amdgcn_mfma_f32_16x16x32_bf16(af[1], bf, acc[1][ntl], 0, 0, 0);
    }
    __syncthreads();
  }
#pragma unroll
  for (int mt = 0; mt < 2; ++mt)
#pragma unroll
    for (int ntl = 0; ntl < 8; ++ntl) {
      int n = N0 + ntl * 16 + lrow;
      float bias = b_in[n];
#pragma unroll
      for (int r = 0; r < 4; ++r) {
        int row = Mtile * 128 + wv * 32 + mt * 16 + lq * 4 + r;
        float v = acc[mt][ntl][r] + bias;
        v = v > 0.0f ? v : 0.0f;
        X[row * H_ + n] = f2bf(v);
      }
    }
}

// ---------------- persistent LSTM: 8 groups (=XCD if round-robin) x 32 blocks ----------------
// Exchange chunk = {bf16 h[2c], bf16 h[2c+1], u32 tag}. Producers dual-store: plain
// (write-through -> shared XCD L2, consumed by sc0 loads) + agent-scope duplicate
// (bufSlow, consumed if topology assumption fails). Sticky per-wave fast/slow mode.
__device__ __forceinline__ void stageX(unsigned short* dst, const unsigned short* src, int tid) {
#pragma unroll
  for (int i = 0; i < 4; ++i) {
    int c = i * 256 + tid;
    int row = c >> 6;
    int col = (c & 63) * 8;
    uint4 v = *(const uint4*)&src[row * H_ + col];
    *(uint4*)&dst[row * 520 + col] = v;
  }
}

// one poll round over this thread's 16 contiguous chunks (128B), L1-bypass (sc0)
__device__ __forceinline__ int fast_round(unsigned long long addr, unsigned int e,
                                          unsigned int* pay) {
  u32x4_ r0, r1, r2, r3, r4, r5, r6, r7;
  asm volatile(
      "global_load_dwordx4 %0, %8, off sc0\n\t"
      "global_load_dwordx4 %1, %8, off offset:16 sc0\n\t"
      "global_load_dwordx4 %2, %8, off offset:32 sc0\n\t"
      "global_load_dwordx4 %3, %8, off offset:48 sc0\n\t"
      "global_load_dwordx4 %4, %8, off offset:64 sc0\n\t"
      "global_load_dwordx4 %5, %8, off offset:80 sc0\n\t"
      "global_load_dwordx4 %6, %8, off offset:96 sc0\n\t"
      "global_load_dwordx4 %7, %8, off offset:112 sc0\n\t"
      "s_waitcnt vmcnt(0)"
      : "=&v"(r0), "=&v"(r1), "=&v"(r2), "=&v"(r3), "=&v"(r4), "=&v"(r5), "=&v"(r6), "=&v"(r7)
      : "v"(addr)
      : "memory");
  int ok = (r0.y == e) & (r0.w == e) & (r1.y == e) & (r1.w == e) & (r2.y == e) & (r2.w == e) &
           (r3.y == e) & (r3.w == e) & (r4.y == e) & (r4.w == e) & (r5.y == e) & (r5.w == e) &
           (r6.y == e) & (r6.w == e) & (r7.y == e) & (r7.w == e);
  pay[0] = r0.x; pay[1] = r0.z; pay[2] = r1.x; pay[3] = r1.z;
  pay[4] = r2.x; pay[5] = r2.z; pay[6] = r3.x; pay[7] = r3.z;
  pay[8] = r4.x; pay[9] = r4.z; pay[10] = r5.x; pay[11] = r5.z;
  pay[12] = r6.x; pay[13] = r6.z; pay[14] = r7.x; pay[15] = r7.z;
  return ok;
}

__device__ __forceinline__ void fetch_h(unsigned short* hS, const unsigned long long* fastp,
                                        const unsigned long long* slowp,
                                        const unsigned int* flagp, unsigned int e, int tid,
                                        int ln, int& mode, int budget, int& guard) {
  if (mode == 0) {
    unsigned long long addr = (unsigned long long)(uintptr_t)(fastp + tid * 16);
    unsigned int pay[16];
    int done = 0, rounds = 0, fail = 0;
    for (;;) {
      if (!done) {
        if (fast_round(addr, e, pay)) {
#pragma unroll
          for (int i = 0; i < 16; ++i) *(unsigned int*)&hS[i * 520 + 2 * tid] = pay[i];
          done = 1;
        }
      }
      if (__all(done)) break;
      if (++rounds > budget) { fail = 1; break; }
    }
    if (!fail) return;
    mode = 1;   // sticky fallback (wave-uniform: rounds/budget uniform)
  }
  {  // slow: agent flag gate, then agent tagged bulk load
    const unsigned int* fp = flagp + (ln & 31);
    for (;;) {
      unsigned int v = (ln < 32)
                           ? __hip_atomic_load(fp, __ATOMIC_RELAXED, __HIP_MEMORY_SCOPE_AGENT)
                           : e;
      if (__all((int)v >= (int)e)) break;
      if (++guard > 4000000) break;
      __builtin_amdgcn_s_sleep(1);
    }
    const unsigned long long* p = slowp + tid * 16;
    unsigned int fresh = 0;
    while (fresh != 0xffffu) {
#pragma unroll
      for (int i = 0; i < 16; ++i) {
        if (!((fresh >> i) & 1u)) {
          unsigned long long v =
              __hip_atomic_load(p + i, __ATOMIC_RELAXED, __HIP_MEMORY_SCOPE_AGENT);
          if ((unsigned int)(v >> 32) == e) {
            fresh |= 1u << i;
            *(unsigned int*)&hS[i * 520 + 2 * tid] = (unsigned int)v;
          }
        }
      }
      if (++guard > 4000000) break;
    }
  }
}

__global__ __launch_bounds__(256, 1) void k_lstm(
    const float* __restrict__ Wih0, const float* __restrict__ Whh0,
    const float* __restrict__ bih0, const float* __restrict__ bhh0,
    const float* __restrict__ Wih1, const float* __restrict__ Whh1,
    const float* __restrict__ bih1, const float* __restrict__ bhh1,
    const unsigned short* __restrict__ X, unsigned long long* __restrict__ bufFA,
    unsigned long long* __restrict__ bufFB, unsigned long long* __restrict__ bufSA,
    unsigned long long* __restrict__ bufSB, unsigned int* __restrict__ flags,
    float* __restrict__ out_h, float* __restrict__ out_c) {
  __shared__ __align__(16) unsigned short hS[16 * 520];
  __shared__ __align__(16) unsigned short xS[2][16 * 520];
  __shared__ __align__(16) float gS[64 * 20];
  __shared__ float b0cS[64], b1cS[64];

  const int tid = threadIdx.x;
  const int g = blockIdx.x & 7;        // group == XCD if dispatch is round-robin
  const int bc = blockIdx.x >> 3;      // 0..31 : h-cols j0..j0+15
  const int j0 = bc * 16;
  const int r0 = g * 16;
  const int wv = tid >> 6, ln = tid & 63;
  const int lrow = ln & 15, lq = ln >> 4;
  const int n_local = wv * 16 + lrow;
  const int gcol = ((n_local >> 4) << 9) + j0 + (n_local & 15);

  bf16x8 Bf0[32], Bf1[16];
  {
    const float* s0 = Wih0 + gcol * H_;
    const float* s1 = Whh0 + gcol * H_;
#pragma unroll
    for (int ks = 0; ks < 32; ++ks) {
      int k = (ks & 15) * 32 + lq * 8;
      const float* s = (ks < 16) ? (s0 + k) : (s1 + k);
      ushortx8 u;
#pragma unroll
      for (int j = 0; j < 8; ++j) u[j] = f2bf(s[j]);
      Bf0[ks] = __builtin_bit_cast(bf16x8, u);
    }
    const float* sa = Wih1 + gcol * H_;
    const float* sb = Whh1 + gcol * H_;
#pragma unroll
    for (int ks = 0; ks < 16; ++ks) {
      int k = ks * 32 + lq * 8;
      ushortx8 u;
#pragma unroll
      for (int j = 0; j < 8; ++j) u[j] = f2bf(sa[k + j] + sb[k + j]);
      Bf1[ks] = __builtin_bit_cast(bf16x8, u);
    }
  }
  if (tid < 64) {
    int g2 = ((tid >> 4) << 9) + j0 + (tid & 15);
    b0cS[tid] = bih0[g2] + bhh0[g2];
    b1cS[tid] = bih1[g2] + bhh1[g2];
  }

  unsigned long long* fA = bufFA + g * 4096;
  unsigned long long* fB = bufFB + g * 4096;
  unsigned long long* sA = bufSA + g * 4096;
  unsigned long long* sB = bufSB + g * 4096;
  unsigned int* flagg = flags + g * 32;
  unsigned int* myflag = flagg + bc;

  const int erow = tid >> 4, ecol = tid & 15;
  const int fragOff = lrow * 520 + lq * 8;
  const int cidx = (bc * 8 + (ecol >> 1)) * 16 + erow;
  float c_reg = 0.0f, cp_v = 0.0f;
  int mode = 0, guard = 0;

  stageX(xS[0], X + (0 * B_ + r0) * H_, tid);
  __syncthreads();
  // alignment (e=1): bound startup skew so the first fast probe is meaningful
  if (tid == 0) __hip_atomic_store(myflag, 1u, __ATOMIC_RELAXED, __HIP_MEMORY_SCOPE_AGENT);
  {
    const unsigned int* fp = flagg + (ln & 31);
    for (;;) {
      unsigned int v =
          (ln < 32) ? __hip_atomic_load(fp, __ATOMIC_RELAXED, __HIP_MEMORY_SCOPE_AGENT) : 1u;
      if (__all((int)v >= 1)) break;
      if (++guard > 4000000) break;
      __builtin_amdgcn_s_sleep(1);
    }
  }
  __syncthreads();

#pragma unroll 1
  for (int t = 0; t < T_; ++t) {
    // ======== cell 0: gates = x_t@Wih0^T + h1_{t-1}@Whh0^T + b ========
    f32x4 ax0 = (f32x4){0.f, 0.f, 0.f, 0.f}, ax1 = (f32x4){0.f, 0.f, 0.f, 0.f};
    const unsigned short* xcur = xS[t & 1];
#pragma unroll
    for (int ks = 0; ks < 8; ++ks) {
      bf16x8 a = __builtin_bit_cast(bf16x8, *(const ushortx8*)&xcur[fragOff + ks * 32]);
      ax0 = __builtin_amdgcn_mfma_f32_16x16x32_bf16(a, Bf0[ks], ax0, 0, 0, 0);
      bf16x8 b = __builtin_bit_cast(bf16x8, *(const ushortx8*)&xcur[fragOff + (ks + 8) * 32]);
      ax1 = __builtin_amdgcn_mfma_f32_16x16x32_bf16(b, Bf0[ks + 8], ax1, 0, 0, 0);
    }
    f32x4 acc;
    if (t > 0) {
      fetch_h(hS, fB, sB, flagg, (unsigned int)(2 * t + 1), tid, ln, mode, 20000, guard);
      __syncthreads();
      f32x4 ah0 = (f32x4){0.f, 0.f, 0.f, 0.f}, ah1 = (f32x4){0.f, 0.f, 0.f, 0.f};
#pragma unroll
      for (int ks = 0; ks < 8; ++ks) {
        bf16x8 a = __builtin_bit_cast(bf16x8, *(const ushortx8*)&hS[fragOff + ks * 32]);
        ah0 = __builtin_amdgcn_mfma_f32_16x16x32_bf16(a, Bf0[16 + ks], ah0, 0, 0, 0);
        bf16x8 b = __builtin_bit_cast(bf16x8, *(const ushortx8*)&hS[fragOff + (ks + 8) * 32]);
        ah1 = __builtin_amdgcn_mfma_f32_16x16x32_bf16(b, Bf0[24 + ks], ah1, 0, 0, 0);
      }
      acc = (ax0 + ax1) + (ah0 + ah1);
    } else {
      acc = ax0 + ax1;   // h_{-1} == 0
    }
    *(f32x4*)&gS[n_local * 20 + lq * 4] = acc;
    __syncthreads();
    float hv;
    {
      float iv = gS[(ecol) * 20 + erow] + b0cS[ecol];
      float fv = gS[(16 + ecol) * 20 + erow] + b0cS[16 + ecol];
      float gv = gS[(32 + ecol) * 20 + erow] + b0cS[32 + ecol];
      float ov = gS[(48 + ecol) * 20 + erow] + b0cS[48 + ecol];
      cp_v = sigm(fv) * c_reg + sigm(iv) * tanhf_(gv);
      hv = sigm(ov) * tanhf_(cp_v);
    }
    {  // publish h0_t, e = 2t+2 (dual store, then drain + flag)
      unsigned int e = (unsigned int)(2 * t + 2);
      float hp = __shfl(hv, ln ^ 1, 64);
      unsigned short lo = f2bf((ecol & 1) ? hp : hv);
      unsigned short hi = f2bf((ecol & 1) ? hv : hp);
      unsigned long long chunk = (unsigned long long)lo | ((unsigned long long)hi << 16) |
                                 ((unsigned long long)e << 32);
      if ((ecol & 1) == 0)
        __hip_atomic_store(fA + cidx, chunk, __ATOMIC_RELAXED, __HIP_MEMORY_SCOPE_WORKGROUP);
      else
        __hip_atomic_store(sA + cidx, chunk, __ATOMIC_RELAXED, __HIP_MEMORY_SCOPE_AGENT);
      __syncthreads();
      if (tid == 0) __hip_atomic_store(myflag, e, __ATOMIC_RELAXED, __HIP_MEMORY_SCOPE_AGENT);
    }

    // ======== cell 1: gates = h0_t@(Wih1+Whh1)^T + b ========
    fetch_h(hS, fA, sA, flagg, (unsigned int)(2 * t + 2), tid, ln, mode, (t == 0) ? 400 : 20000,
            guard);
    __syncthreads();
    if (t + 1 < T_) stageX(xS[(t + 1) & 1], X + ((t + 1) * B_ + r0) * H_, tid);  // early prefetch
    f32x4 a10 = (f32x4){0.f, 0.f, 0.f, 0.f}, a11 = (f32x4){0.f, 0.f, 0.f, 0.f};
#pragma unroll
    for (int ks = 0; ks < 8; ++ks) {
      bf16x8 a = __builtin_bit_cast(bf16x8, *(const ushortx8*)&hS[fragOff + ks * 32]);
      a10 = __builtin_amdgcn_mfma_f32_16x16x32_bf16(a, Bf1[ks], a10, 0, 0, 0);
      bf16x8 b = __builtin_bit_cast(bf16x8, *(const ushortx8*)&hS[fragOff + (ks + 8) * 32]);
      a11 = __builtin_amdgcn_mfma_f32_16x16x32_bf16(b, Bf1[ks + 8], a11, 0, 0, 0);
    }
    acc = a10 + a11;
    *(f32x4*)&gS[n_local * 20 + lq * 4] = acc;
    __syncthreads();
    {
      float iv = gS[(ecol) * 20 + erow] + b1cS[ecol];
      float fv = gS[(16 + ecol) * 20 + erow] + b1cS[16 + ecol];
      float gv = gS[(32 + ecol) * 20 + erow] + b1cS[32 + ecol];
      float ov = gS[(48 + ecol) * 20 + erow] + b1cS[48 + ecol];
      float cn = sigm(fv) * cp_v + sigm(iv) * tanhf_(gv);
      hv = sigm(ov) * tanhf_(cn);
      c_reg = cn;
      if (t == T_ - 1) {
        out_h[(r0 + erow) * H_ + j0 + ecol] = hv;
        out_c[(r0 + erow) * H_ + j0 + ecol] = cn;
      }
    }
    {  // publish h1_t, e = 2t+3
      unsigned int e = (unsigned int)(2 * t + 3);
      float hp = __shfl(hv, ln ^ 1, 64);
      unsigned short lo = f2bf((ecol & 1) ? hp : hv);
      unsigned short hi = f2bf((ecol & 1) ? hv : hp);
      unsigned long long chunk = (unsigned long long)lo | ((unsigned long long)hi << 16) |
                                 ((unsigned long long)e << 32);
      if ((ecol & 1) == 0)
        __hip_atomic_store(fB + cidx, chunk, __ATOMIC_RELAXED, __HIP_MEMORY_SCOPE_WORKGROUP);
      else
        __hip_atomic_store(sB + cidx, chunk, __ATOMIC_RELAXED, __HIP_MEMORY_SCOPE_AGENT);
      __syncthreads();
      if (tid == 0) __hip_atomic_store(myflag, e, __ATOMIC_RELAXED, __HIP_MEMORY_SCOPE_AGENT);
    }
  }
}

// ---------------- heads: cont_out + cls_out (f32) ----------------
__global__ __launch_bounds__(256) void k_heads(const float* __restrict__ h,
                                               const float* __restrict__ W_out,
                                               const float* __restrict__ b_out,
                                               const float* __restrict__ W_cls,
                                               const float* __restrict__ b_cls,
                                               float* __restrict__ out) {
  int o = blockIdx.x * 256 + threadIdx.x;
  if (o < B_ * NCONT_) {
    int b = o / NCONT_;
    int n = o - b * NCONT_;
    float acc = b_out[n];
    const float* hb = h + b * H_;
    for (int k = 0; k < H_; k += 4) {
      acc += hb[k] * W_out[k * NCONT_ + n] + hb[k + 1] * W_out[(k + 1) * NCONT_ + n] +
             hb[k + 2] * W_out[(k + 2) * NCONT_ + n] + hb[k + 3] * W_out[(k + 3) * NCONT_ + n];
    }
    out[o] = acc;
  } else {
    int oo = o - B_ * NCONT_;
    int b = oo >> 9;
    int r = oo & 511;
    int ci = r >> 4, cd = r & 15;
    float acc = b_cls[ci * 16 + cd];
    const float* hb = h + b * H_;
    const float* wc = W_cls + ci * 512 * 16 + cd;
    for (int k = 0; k < H_; k += 4) {
      acc += hb[k] * wc[k * 16] + hb[k + 1] * wc[(k + 1) * 16] + hb[k + 2] * wc[(k + 2) * 16] +
             hb[k + 3] * wc[(k + 3) * 16];
    }
    out[B_ * NCONT_ + oo] = acc;
  }
}

extern "C" void kernel_launch(void* const* d_in, const int* in_sizes, int n_in,
                              void* d_out, int out_size, void* d_ws, size_t ws_size,
                              hipStream_t stream) {
  const int* unscaled = (const int*)d_in[0];
  const float* scaled = (const float*)d_in[1];
  const float* emb = (const float*)d_in[2];
  const float* W_in = (const float*)d_in[3];
  const float* b_in = (const float*)d_in[4];
  const float* Wih0 = (const float*)d_in[5];
  const float* Whh0 = (const float*)d_in[6];
  const float* bih0 = (const float*)d_in[7];
  const float* bhh0 = (const float*)d_in[8];
  const float* Wih1 = (const float*)d_in[9];
  const float* Whh1 = (const float*)d_in[10];
  const float* bih1 = (const float*)d_in[11];
  const float* bhh1 = (const float*)d_in[12];
  const float* W_out = (const float*)d_in[13];
  const float* b_out = (const float*)d_in[14];
  const float* W_cls = (const float*)d_in[15];
  const float* b_cls = (const float*)d_in[16];

  const size_t o_feat = 0;             // 23068672
  const size_t o_X = 23068672;         // 33554432
  const size_t o_WinT = 56623104;      // 360448
  const size_t o_bufFA = 56983552;     // 262144
  const size_t o_bufFB = 57245696;     // 262144
  const size_t o_bufSA = 57507840;     // 262144
  const size_t o_bufSB = 57769984;     // 262144
  const size_t o_flags = 58032128;     // 1024
  const size_t WS_NEED = 58033152;
  if (ws_size < WS_NEED) return;

  char* ws = (char*)d_ws;
  unsigned short* FEAT = (unsigned short*)(ws + o_feat);
  unsigned short* X = (unsigned short*)(ws + o_X);
  unsigned short* W_inT = (unsigned short*)(ws + o_WinT);
  unsigned long long* bufFA = (unsigned long long*)(ws + o_bufFA);
  unsigned long long* bufFB = (unsigned long long*)(ws + o_bufFB);
  unsigned long long* bufSA = (unsigned long long*)(ws + o_bufSA);
  unsigned long long* bufSB = (unsigned long long*)(ws + o_bufSB);
  unsigned int* flags = (unsigned int*)(ws + o_flags);

  float* out = (float*)d_out;
  float* out_h = out + 77824;
  float* out_c = out + 143360;

  k_prep<<<704, 256, 0, stream>>>(W_in, W_inT);
  k_feat<<<8192, 256, 0, stream>>>(unscaled, scaled, emb, FEAT);
  k_gemm1<<<1024, 256, 0, stream>>>(FEAT, W_inT, b_in, X);
  k_lstm<<<256, 256, 0, stream>>>(Wih0, Whh0, bih0, bhh0, Wih1, Whh1, bih1, bhh1, X, bufFA, bufFB,
                                  bufSA, bufSB, flags, out_h, out_c);
  k_heads<<<304, 256, 0, stream>>>(out_h, W_out, b_out, W_cls, b_cls, out);
}